// Round 7
// baseline (325.690 us; speedup 1.0000x reference)
//
#include <hip/hip_runtime.h>
#include <hip/hip_bf16.h>
#include <math.h>

#define NN   50000
#define EE   800000
#define INF  512
#define HIDF 256
#define OUTF 64
#define MTILES (NN/16)   // 3125

using short8 = __attribute__((ext_vector_type(8))) short;
using short4v = __attribute__((ext_vector_type(4))) short;
using f32x4  = __attribute__((ext_vector_type(4))) float;
using i32x4  = __attribute__((ext_vector_type(4))) int;

typedef __attribute__((address_space(1))) const void gas_void;
typedef __attribute__((address_space(3))) void las_void;

static __device__ __forceinline__ short f2bf(float f){
  unsigned u = __builtin_bit_cast(unsigned, f);
  u += 0x7fff + ((u >> 16) & 1);        // round-to-nearest-even
  return (short)(u >> 16);
}
static __device__ __forceinline__ float bf2f(short s){
  unsigned u = ((unsigned)(unsigned short)s) << 16;
  return __builtin_bit_cast(float, u);
}

// ---- fused prep: row_ptr (0..195) | W1 pack (196..707) | W2^T (708..771)
// ---- | drop_mask bit-pack (772..3896): 51.2 MB int32 -> 1.6 MB u16 --------
__global__ void k_prep(const int* __restrict__ a_row, int* __restrict__ row_ptr,
                       const float* __restrict__ W1, short* __restrict__ W1p,
                       const float* __restrict__ W2, short* __restrict__ W2bT,
                       const int* __restrict__ drop, unsigned short* __restrict__ dropP){
  int b = blockIdx.x, tid = threadIdx.x;
  if (b < 196){
    int i = b * 256 + tid;
    if (i > NN) return;
    int lo = 0, hi = EE;
    while (lo < hi){ int mid = (lo + hi) >> 1; if (a_row[mid] < i) lo = mid + 1; else hi = mid; }
    row_ptr[i] = lo;
  } else if (b < 708){
    int idx = (b - 196) * 256 + tid;        // 512*256 elements
    int k = idx >> 8, col = idx & 255;
    int kk = k >> 5, k2 = k & 31;
    W1p[((kk << 8) + col) * 32 + k2] = f2bf(W1[idx]);
  } else if (b < 772){
    int idx = (b - 708) * 256 + tid;        // 256*64 elements
    int k = idx >> 6, n = idx & 63;
    W2bT[n * HIDF + k] = f2bf(W2[idx]);
  } else {
    // word w covers (row = w/16, feature block (w%16)*16..+15) = ints [w*16, w*16+16)
    int w = (b - 772) * 256 + tid;          // 800000 words = 3125 blocks exactly
    const i32x4* dp = (const i32x4*)(drop + w * 16);
    i32x4 m0 = __builtin_nontemporal_load(dp);
    i32x4 m1 = __builtin_nontemporal_load(dp + 1);
    i32x4 m2 = __builtin_nontemporal_load(dp + 2);
    i32x4 m3 = __builtin_nontemporal_load(dp + 3);
    unsigned bits =
        (unsigned)(m0[0] & 1)        | ((unsigned)(m0[1] & 1) << 1)  |
        ((unsigned)(m0[2] & 1) << 2) | ((unsigned)(m0[3] & 1) << 3)  |
        ((unsigned)(m1[0] & 1) << 4) | ((unsigned)(m1[1] & 1) << 5)  |
        ((unsigned)(m1[2] & 1) << 6) | ((unsigned)(m1[3] & 1) << 7)  |
        ((unsigned)(m2[0] & 1) << 8) | ((unsigned)(m2[1] & 1) << 9)  |
        ((unsigned)(m2[2] & 1) << 10)| ((unsigned)(m2[3] & 1) << 11) |
        ((unsigned)(m3[0] & 1) << 12)| ((unsigned)(m3[1] & 1) << 13) |
        ((unsigned)(m3[2] & 1) << 14)| ((unsigned)(m3[3] & 1) << 15);
    dropP[w] = (unsigned short)bits;
  }
}

// ---------------- GEMM1: XW1b[NN,HIDF](bf16) = X[NN,INF] @ W1 ----------------
// 2-phase pipelined (validated round 2).  X loads are NON-TEMPORAL: X is
// 102 MB read-once and was evicting XW1b from L3 right before spmm1 needed it.
__global__ __launch_bounds__(256) void k_gemm1(const float* __restrict__ X,
                                               const short* __restrict__ W1p,
                                               short* __restrict__ XW1b){
  __shared__ short lds[2][256 * 32];          // 2 x 16 KB B panels
  int wave = threadIdx.x >> 6, lane = threadIdx.x & 63;
  int l16 = lane & 15, quad = lane >> 4;
  int m0 = blockIdx.x * 64 + wave * 16;       // 16 rows per wave
  int r = min(m0 + l16, NN - 1);              // clamp loads; stores guarded
  const f32x4* ap = (const f32x4*)(X + (size_t)r * INF + quad * 8);

  f32x4 acc[16];
  #pragma unroll
  for (int t = 0; t < 16; t++) acc[t] = (f32x4){0.f,0.f,0.f,0.f};

  auto stage = [&](int buf, int kk){
    const char* src = (const char*)(W1p + kk * (256 * 32));
    char* dst = (char*)&lds[buf][0];
    #pragma unroll
    for (int j = 0; j < 4; j++){
      int off = wave * 4096 + j * 1024;
      __builtin_amdgcn_global_load_lds((gas_void*)(src + off + lane * 16),
                                       (las_void*)(dst + off), 16, 0, 0);
    }
  };

  stage(0, 0);
  f32x4 a0 = __builtin_nontemporal_load(ap);
  f32x4 a1 = __builtin_nontemporal_load(ap + 1);
  __syncthreads();                            // drains vmcnt -> lds[0] ready

  for (int kk = 0; kk < 16; kk++){
    int cur = kk & 1;
    f32x4 na0, na1;
    if (kk < 15){
      stage(cur ^ 1, kk + 1);
      na0 = __builtin_nontemporal_load(ap + (kk + 1) * 8);
      na1 = __builtin_nontemporal_load(ap + (kk + 1) * 8 + 1);
    }
    short8 af;
    af[0]=f2bf(a0[0]); af[1]=f2bf(a0[1]); af[2]=f2bf(a0[2]); af[3]=f2bf(a0[3]);
    af[4]=f2bf(a1[0]); af[5]=f2bf(a1[1]); af[6]=f2bf(a1[2]); af[7]=f2bf(a1[3]);
    const short* bp = &lds[cur][0] + l16 * 32 + quad * 8;
    #pragma unroll
    for (int nt = 0; nt < 16; nt++){
      short8 bf = *(const short8*)(bp + nt * 512);   // (nt*16 cols) * 32 shorts
      acc[nt] = __builtin_amdgcn_mfma_f32_16x16x32_bf16(af, bf, acc[nt], 0, 0, 0);
    }
    a0 = na0; a1 = na1;
    __syncthreads();                          // next panel arrived; cur free to reuse
  }

  #pragma unroll
  for (int nt = 0; nt < 16; nt++){
    int col = nt*16 + l16;
    #pragma unroll
    for (int rr = 0; rr < 4; rr++){
      int row = m0 + quad*4 + rr;
      if (row < NN) XW1b[(size_t)row * HIDF + col] = f2bf(acc[nt][rr]);
    }
  }
}

// ---- SpMM1 + ReLU + dropout (round-5 preload+shfl structure kept) --------
// Change this round: dropout mask read is 2 B/lane from the bit-packed dropP
// (was 64 B/lane from int32 drop_mask — 51.2 MB off this kernel's HBM bill).
__global__ __launch_bounds__(256) void k_spmm1(const int* __restrict__ row_ptr,
                                               const int* __restrict__ a_col,
                                               const float* __restrict__ a_val,
                                               const short* __restrict__ XW1b,
                                               const unsigned short* __restrict__ dropP,
                                               short* __restrict__ hb){
  int wave = threadIdx.x >> 6, lane = threadIdx.x & 63;
  int r = blockIdx.x * 4 + wave;
  int s = row_ptr[r], e = row_ptr[r+1];
  int g = lane >> 4;          // edge subgroup (4 edges per step)
  int c16 = lane & 15;        // this lane covers cols c16*16 .. +15
  int d = e - s;

  int   lim = d < 64 ? d : 64;
  bool  lv  = lane < lim;
  float myv = lv ? a_val[s + lane] : 0.f;   // coalesced 64-edge preload
  int   myc = lv ? a_col[s + lane] : 0;

  float acc[16];
  #pragma unroll
  for (int j = 0; j < 16; j++) acc[j] = 0.f;

  int nsteps = (lim + 3) >> 2;              // 4 edges per step
  for (int t = 0; t < nsteps; t += 2){      // t always even; shfl idx <= 63
    int e0 = 4*t + g, e1 = 4*t + 4 + g;
    float v0 = __shfl(myv, e0);  int c0 = __shfl(myc, e0);
    float v1 = __shfl(myv, e1);  int c1 = __shfl(myc, e1);  // v=0 past row end
    const short* p0 = XW1b + (c0 << 8) + c16 * 16;          // c*HIDF fits int
    const short* p1 = XW1b + (c1 << 8) + c16 * 16;
    short8 xa0 = *(const short8*)(p0), xb0 = *(const short8*)(p0 + 8);
    short8 xa1 = *(const short8*)(p1), xb1 = *(const short8*)(p1 + 8);
    #pragma unroll
    for (int j = 0; j < 8; j++){
      acc[j]   += v0 * bf2f(xa0[j]);  acc[j+8] += v0 * bf2f(xb0[j]);
      acc[j]   += v1 * bf2f(xa1[j]);  acc[j+8] += v1 * bf2f(xb1[j]);
    }
  }
  if (d > 64){                              // correctness fallback, ~never taken
    for (int i = s + 64 + g; i < e; i += 4){
      float v = a_val[i];  int c = a_col[i];
      const short* p = XW1b + (c << 8) + c16 * 16;
      short8 xa = *(const short8*)(p), xb = *(const short8*)(p + 8);
      #pragma unroll
      for (int j = 0; j < 8; j++){
        acc[j] += v * bf2f(xa[j]);  acc[j+8] += v * bf2f(xb[j]);
      }
    }
  }

  #pragma unroll
  for (int j = 0; j < 16; j++){
    acc[j] += __shfl_xor(acc[j], 16);
    acc[j] += __shfl_xor(acc[j], 32);
  }
  if (lane < 16){
    unsigned bits = dropP[r * 16 + c16];
    short8 o0, o1;
    #pragma unroll
    for (int j = 0; j < 8; j++){
      o0[j] = f2bf(fmaxf(acc[j],   0.f) * (((bits >> j)     & 1) ? 2.0f : 0.0f));
      o1[j] = f2bf(fmaxf(acc[j+8], 0.f) * (((bits >> (j+8)) & 1) ? 2.0f : 0.0f));
    }
    short* hp = hb + (size_t)r * HIDF + c16 * 16;
    *(short8*)(hp)     = o0;
    *(short8*)(hp + 8) = o1;
  }
}

// ---------------- GEMM2: HW2b[NN,OUTF](bf16) = h[NN,HIDF] @ W2 ----------------
// hb is read-once here -> non-temporal (protects HW2b/XW1b L3 residency).
__global__ __launch_bounds__(256) void k_gemm2(const short* __restrict__ A,  // hb
                                               const short* __restrict__ BT, // [OUTF][HIDF]
                                               short* __restrict__ C){
  int wave = threadIdx.x >> 6, lane = threadIdx.x & 63;
  int tile_m = blockIdx.x * 4 + wave;
  if (tile_m >= MTILES) return;
  int m0 = tile_m * 16, l16 = lane & 15, quad = lane >> 4;

  f32x4 acc[4];
  #pragma unroll
  for (int t = 0; t < 4; t++) acc[t] = (f32x4){0.f,0.f,0.f,0.f};

  const short8* ar = (const short8*)(A + (size_t)(m0 + l16) * HIDF + quad * 8);
  for (int kk = 0; kk < HIDF/32; kk++){
    short8 af = __builtin_nontemporal_load(ar + kk * 4);   // stride 32 shorts
    #pragma unroll
    for (int nt = 0; nt < 4; nt++){
      short8 bf = *(const short8*)(BT + (size_t)(nt*16 + l16) * HIDF + kk*32 + quad*8);
      acc[nt] = __builtin_amdgcn_mfma_f32_16x16x32_bf16(af, bf, acc[nt], 0, 0, 0);
    }
  }
  #pragma unroll
  for (int nt = 0; nt < 4; nt++){
    int col = nt*16 + l16;
    #pragma unroll
    for (int r = 0; r < 4; r++)
      C[(size_t)(m0 + quad*4 + r) * OUTF + col] = f2bf(acc[nt][r]);
  }
}

// -- SpMM2 + log_softmax: round-5 preload+shfl structure kept --
__global__ __launch_bounds__(256) void k_spmm2_lsm(const int* __restrict__ row_ptr,
                                                   const int* __restrict__ a_col,
                                                   const float* __restrict__ a_val,
                                                   const short* __restrict__ HW2b,
                                                   float* __restrict__ out){
  int wave = threadIdx.x >> 6, lane = threadIdx.x & 63;
  int r = blockIdx.x * 4 + wave;
  int s = row_ptr[r], e = row_ptr[r+1];
  int g = lane >> 4;          // edge subgroup
  int c4 = lane & 15;         // this lane covers classes c4*4 .. c4*4+3
  int d = e - s;

  int   lim = d < 64 ? d : 64;
  bool  lv  = lane < lim;
  float myv = lv ? a_val[s + lane] : 0.f;
  int   myc = lv ? a_col[s + lane] : 0;

  float acc[4] = {0,0,0,0};

  int nsteps = (lim + 3) >> 2;
  for (int t = 0; t < nsteps; t += 2){
    int e0 = 4*t + g, e1 = 4*t + 4 + g;
    float v0 = __shfl(myv, e0);  int c0 = __shfl(myc, e0);
    float v1 = __shfl(myv, e1);  int c1 = __shfl(myc, e1);
    short4v x0 = *(const short4v*)(HW2b + (c0 << 6) + c4 * 4);
    short4v x1 = *(const short4v*)(HW2b + (c1 << 6) + c4 * 4);
    #pragma unroll
    for (int j = 0; j < 4; j++){
      acc[j] += v0 * bf2f(x0[j]);
      acc[j] += v1 * bf2f(x1[j]);
    }
  }
  if (d > 64){
    for (int i = s + 64 + g; i < e; i += 4){
      float v = a_val[i];  int c = a_col[i];
      short4v x = *(const short4v*)(HW2b + (c << 6) + c4 * 4);
      #pragma unroll
      for (int j = 0; j < 4; j++) acc[j] += v * bf2f(x[j]);
    }
  }

  #pragma unroll
  for (int j = 0; j < 4; j++){
    acc[j] += __shfl_xor(acc[j], 16);
    acc[j] += __shfl_xor(acc[j], 32);
  }
  // log_softmax across 64 classes (all lanes now hold identical per-c4 values)
  float m = fmaxf(fmaxf(acc[0], acc[1]), fmaxf(acc[2], acc[3]));
  #pragma unroll
  for (int o = 1; o <= 8; o <<= 1) m = fmaxf(m, __shfl_xor(m, o));
  float ssum = expf(acc[0]-m) + expf(acc[1]-m) + expf(acc[2]-m) + expf(acc[3]-m);
  #pragma unroll
  for (int o = 1; o <= 8; o <<= 1) ssum += __shfl_xor(ssum, o);
  float ls = logf(ssum);
  if (lane < 16){
    float4 o4 = { acc[0]-m-ls, acc[1]-m-ls, acc[2]-m-ls, acc[3]-m-ls };
    *(float4*)(out + (size_t)r * OUTF + c4 * 4) = o4;
  }
}

extern "C" void kernel_launch(void* const* d_in, const int* in_sizes, int n_in,
                              void* d_out, int out_size, void* d_ws, size_t ws_size,
                              hipStream_t stream) {
  const float* X      = (const float*)d_in[0];
  const float* W1     = (const float*)d_in[1];
  const float* W2     = (const float*)d_in[2];
  const int*   a_row  = (const int*)d_in[3];
  const int*   a_col  = (const int*)d_in[4];
  const float* a_val  = (const float*)d_in[5];
  const int*   drop   = (const int*)d_in[6];
  float*       out    = (float*)d_out;

  char* ws = (char*)d_ws;
  int*            row_ptr = (int*)           (ws);             //   200,704 B
  short*          W1p     = (short*)         (ws + 200704);    //   262,144 B
  short*          W2bT    = (short*)         (ws + 462848);    //    32,768 B
  short*          XW1b    = (short*)         (ws + 495616);    // 25,600,000 B
  short*          hb      = (short*)         (ws + 26095616);  // 25,600,000 B
  short*          HW2b    = (short*)         (ws + 51695616);  //  6,400,000 B
  unsigned short* dropP   = (unsigned short*)(ws + 58095616);  //  1,600,000 B (end ~59.7 MB)

  k_prep<<<3897, 256, 0, stream>>>(a_row, row_ptr, W1, W1p, W2, W2bT, drop, dropP);
  k_gemm1<<<(NN + 63)/64, 256, 0, stream>>>(X, W1p, XW1b);
  k_spmm1<<<NN/4, 256, 0, stream>>>(row_ptr, a_col, a_val, XW1b, dropP, hb);
  k_gemm2<<<(MTILES + 3)/4, 256, 0, stream>>>(hb, W2bT, HW2b);
  k_spmm2_lsm<<<NN/4, 256, 0, stream>>>(row_ptr, a_col, a_val, HW2b, out);
}